// Round 1
// 64.360 us; speedup vs baseline: 1.0437x; 1.0437x over previous
//
#include <hip/hip_runtime.h>
#include <math.h>

#define LAYERS  3
#define PATCHES 196   // 14*14

// Key identity: the gate set {RX(w), CNOT(0,1), CNOT(2,3), RZ(w)} never couples
// wire-pair (0,1) with (2,3), so the 4-qubit state is always a tensor product
// psi_A (wires 0,1) x psi_B (wires 2,3). Each pair evolves as an independent
// 2-qubit (4-amplitude) circuit, and since both stay norm-1, <Z_0>,<Z_1> come
// from psi_A alone and <Z_2>,<Z_3> from psi_B alone. This is ~3x less VALU
// work than the 16-amplitude simulation, with two independent chains for ILP.
//
// RZ diagonal per pair per layer has only 2 distinct angles:
//   theta(bu,bv) = (+-phi_u +- phi_v)/2  ->  S=(phi_u+phi_v)/2, D=(phi_u-phi_v)/2
//   ph[0]=(cS,-sS) ph[1]=(cD,-sD) ph[2]=(cD,sD) ph[3]=(cS,sS)
// so each thread computes them in registers from qp (uniform -> s_load);
// no LDS phase tables, no pre-circuit barrier, no ds_reads in the hot loop.

__device__ __forceinline__ void pair_layer(
    float r[4], float im[4],
    float cu, float su, float cv, float sv,
    float cS, float sS, float cD, float sD)
{
    // RX on u (high bit): butterflies (0,2),(1,3); new = c*a - i*s*a'
    {
        float t0r=r[0], t0i=im[0], t1r=r[2], t1i=im[2];
        r[0]=fmaf(cu,t0r, su*t1i); im[0]=fmaf(cu,t0i,-su*t1r);
        r[2]=fmaf(cu,t1r, su*t0i); im[2]=fmaf(cu,t1i,-su*t0r);
    }
    {
        float t0r=r[1], t0i=im[1], t1r=r[3], t1i=im[3];
        r[1]=fmaf(cu,t0r, su*t1i); im[1]=fmaf(cu,t0i,-su*t1r);
        r[3]=fmaf(cu,t1r, su*t0i); im[3]=fmaf(cu,t1i,-su*t0r);
    }
    // RX on v (low bit): butterflies (0,1),(2,3)
    {
        float t0r=r[0], t0i=im[0], t1r=r[1], t1i=im[1];
        r[0]=fmaf(cv,t0r, sv*t1i); im[0]=fmaf(cv,t0i,-sv*t1r);
        r[1]=fmaf(cv,t1r, sv*t0i); im[1]=fmaf(cv,t1i,-sv*t0r);
    }
    {
        float t0r=r[2], t0i=im[2], t1r=r[3], t1i=im[3];
        r[2]=fmaf(cv,t0r, sv*t1i); im[2]=fmaf(cv,t0i,-sv*t1r);
        r[3]=fmaf(cv,t1r, sv*t0i); im[3]=fmaf(cv,t1i,-sv*t0r);
    }
    // CNOT(u,v): ctrl=1 flips tgt -> swap indices 2,3 (register rename, free)
    { float tr=r[2]; r[2]=r[3]; r[3]=tr; float ti=im[2]; im[2]=im[3]; im[3]=ti; }
    // RZ diagonal at final positions
    {
        float rr, ii;
        rr=r[0]; ii=im[0];  r[0]=fmaf(rr,cS,  ii*sS); im[0]=fmaf(ii,cS, -rr*sS);
        rr=r[1]; ii=im[1];  r[1]=fmaf(rr,cD,  ii*sD); im[1]=fmaf(ii,cD, -rr*sD);
        rr=r[2]; ii=im[2];  r[2]=fmaf(rr,cD, -ii*sD); im[2]=fmaf(ii,cD,  rr*sD);
        rr=r[3]; ii=im[3];  r[3]=fmaf(rr,cS, -ii*sS); im[3]=fmaf(ii,cS,  rr*sS);
    }
}

__global__ __launch_bounds__(256) void quanv_fused(
    const float* __restrict__ x,     // [B,1,28,28]
    const float* __restrict__ qp,    // [LAYERS,WIRES]
    const float* __restrict__ Wt,    // [10,784]
    const float* __restrict__ bias,  // [10]
    float* __restrict__ out)         // [B,10]
{
    __shared__ float wsum[4][10];
    __shared__ float lg[10];

    const int b = blockIdx.x;
    const int t = threadIdx.x;

    // ---- RZ phase sincos: uniform across block, qp via scalar loads ----
    float cS[LAYERS][2], sS[LAYERS][2], cD[LAYERS][2], sD[LAYERS][2];
    #pragma unroll
    for (int l = 0; l < LAYERS; ++l) {
        #pragma unroll
        for (int p = 0; p < 2; ++p) {
            const float pu = qp[l*4 + 2*p], pv = qp[l*4 + 2*p + 1];
            __sincosf(0.5f*(pu+pv), &sS[l][p], &cS[l][p]);
            __sincosf(0.5f*(pu-pv), &sD[l][p], &cD[l][p]);
        }
    }

    float z[4] = {0.f, 0.f, 0.f, 0.f};
    if (t < PATCHES) {
        // ---- direct patch loads + RX sincos (same angles every layer) ----
        const int r = t / 14, cc = t % 14;
        const float* xb = x + (size_t)b * 784;
        const float2 top = *reinterpret_cast<const float2*>(xb + (2*r)*28 + 2*cc);
        const float2 bot = *reinterpret_cast<const float2*>(xb + (2*r+1)*28 + 2*cc);
        float cw[4], sw[4];
        __sincosf(0.5f * top.x, &sw[0], &cw[0]);   // tl -> wire 0
        __sincosf(0.5f * top.y, &sw[1], &cw[1]);   // tr -> wire 1
        __sincosf(0.5f * bot.x, &sw[2], &cw[2]);   // bl -> wire 2
        __sincosf(0.5f * bot.y, &sw[3], &cw[3]);   // br -> wire 3

        // ---- layer 1 analytic: amp_i = m_i * (-i)^popcount(i); CNOT perm
        //      (2<->3) and RZ[0] diagonal folded in ----
        float Ar[4], Ai[4], Br[4], Bi[4];
        {
            const float m0=cw[0]*cw[1], m1=cw[0]*sw[1], m2=sw[0]*cw[1], m3=sw[0]*sw[1];
            const float cs=cS[0][0], ss=sS[0][0], cd=cD[0][0], sd=sD[0][0];
            Ar[0]= m0*cs;  Ai[0]=-m0*ss;   // i=0 -> ti=0, pc=0
            Ar[1]=-m1*sd;  Ai[1]=-m1*cd;   // i=1 -> ti=1, pc=1
            Ar[3]= m2*ss;  Ai[3]=-m2*cs;   // i=2 -> ti=3, pc=1
            Ar[2]=-m3*cd;  Ai[2]=-m3*sd;   // i=3 -> ti=2, pc=2
        }
        {
            const float m0=cw[2]*cw[3], m1=cw[2]*sw[3], m2=sw[2]*cw[3], m3=sw[2]*sw[3];
            const float cs=cS[0][1], ss=sS[0][1], cd=cD[0][1], sd=sD[0][1];
            Br[0]= m0*cs;  Bi[0]=-m0*ss;
            Br[1]=-m1*sd;  Bi[1]=-m1*cd;
            Br[3]= m2*ss;  Bi[3]=-m2*cs;
            Br[2]=-m3*cd;  Bi[2]=-m3*sd;
        }

        // ---- layers 2..3: two independent 2-qubit circuits ----
        #pragma unroll
        for (int l = 1; l < LAYERS; ++l) {
            pair_layer(Ar, Ai, cw[0],sw[0], cw[1],sw[1],
                       cS[l][0],sS[l][0], cD[l][0],sD[l][0]);
            pair_layer(Br, Bi, cw[2],sw[2], cw[3],sw[3],
                       cS[l][1],sS[l][1], cD[l][1],sD[l][1]);
        }

        // ---- <Z_w>: pair A gives wires 0,1; pair B gives wires 2,3 ----
        {
            const float p0=fmaf(Ar[0],Ar[0],Ai[0]*Ai[0]);
            const float p1=fmaf(Ar[1],Ar[1],Ai[1]*Ai[1]);
            const float p2=fmaf(Ar[2],Ar[2],Ai[2]*Ai[2]);
            const float p3=fmaf(Ar[3],Ar[3],Ai[3]*Ai[3]);
            z[0] = (p0+p1) - (p2+p3);   // wire 0 = high bit of pair A
            z[1] = (p0+p2) - (p1+p3);   // wire 1 = low bit
        }
        {
            const float p0=fmaf(Br[0],Br[0],Bi[0]*Bi[0]);
            const float p1=fmaf(Br[1],Br[1],Bi[1]*Bi[1]);
            const float p2=fmaf(Br[2],Br[2],Bi[2]*Bi[2]);
            const float p3=fmaf(Br[3],Br[3],Bi[3]*Bi[3]);
            z[2] = (p0+p1) - (p2+p3);   // wire 2
            z[3] = (p0+p2) - (p1+p3);   // wire 3
        }
    }

    // ---- linear layer, no LDS: thread t owns feature cols 4t..4t+3 ----
    float part[10];
    if (t < PATCHES) {
        const float4* W4 = reinterpret_cast<const float4*>(Wt);  // [10][196]
        #pragma unroll
        for (int k = 0; k < 10; ++k) {
            const float4 w = W4[k * 196 + t];
            part[k] = fmaf(z[0], w.x, fmaf(z[1], w.y, fmaf(z[2], w.z, z[3] * w.w)));
        }
    } else {
        #pragma unroll
        for (int k = 0; k < 10; ++k) part[k] = 0.f;
    }
    #pragma unroll
    for (int k = 0; k < 10; ++k) {
        #pragma unroll
        for (int off = 32; off > 0; off >>= 1)
            part[k] += __shfl_down(part[k], off, 64);
    }
    const int wave = t >> 6, lane = t & 63;
    if (lane == 0) {
        #pragma unroll
        for (int k = 0; k < 10; ++k) wsum[wave][k] = part[k];
    }
    __syncthreads();
    if (t < 10)
        lg[t] = bias[t] + wsum[0][t] + wsum[1][t] + wsum[2][t] + wsum[3][t];
    __syncthreads();
    if (t < 10) {
        float mx = lg[0];
        #pragma unroll
        for (int k = 1; k < 10; ++k) mx = fmaxf(mx, lg[k]);
        float se = 0.f;
        #pragma unroll
        for (int k = 0; k < 10; ++k) se += expf(lg[k] - mx);
        out[b * 10 + t] = lg[t] - (mx + logf(se));
    }
}

extern "C" void kernel_launch(void* const* d_in, const int* in_sizes, int n_in,
                              void* d_out, int out_size, void* d_ws, size_t ws_size,
                              hipStream_t stream) {
    const float* x    = (const float*)d_in[0];
    const float* qp   = (const float*)d_in[1];
    const float* W    = (const float*)d_in[2];
    const float* bias = (const float*)d_in[3];
    float* out = (float*)d_out;

    const int B = in_sizes[0] / 784;  // 1024
    quanv_fused<<<B, 256, 0, stream>>>(x, qp, W, bias, out);
}

// Round 2
// 62.702 us; speedup vs baseline: 1.0713x; 1.0264x over previous
//
#include <hip/hip_runtime.h>
#include <math.h>

#define LAYERS  3
#define PATCHES 196   // 14*14

// Factorized 4-qubit circuit: gate set {RX(w), CNOT(0,1), CNOT(2,3), RZ(w)}
// never couples pair (0,1) with (2,3) -> state is always psi_A (x) psi_B, two
// independent 2-qubit (4-amplitude) circuits; <Z_0,1> from psi_A, <Z_2,3> from
// psi_B.
//
// RZ diagonal per pair per layer has only 2 distinct angles:
//   S=(phi_u+phi_v)/2, D=(phi_u-phi_v)/2
//   ph[0]=(cS,-sS) ph[1]=(cD,-sD) ph[2]=(cD,sD) ph[3]=(cS,sS)
// The 12 (c,s) pairs are UNIFORM across the block -> built once into LDS by
// otherwise-idle threads 208..219, overlapped with the patch threads' pixel
// loads + 4 data-dependent sincos. Patch threads do only 8 trans ops each
// (was 32 when every thread recomputed the uniform table in registers).
//
// Linear layer: lane-parity class split. Even lanes own classes 0-4 for patch
// pair (t, t+1), odd lanes classes 5-9 -> 4 exchange shuffles + 25 butterfly
// shuffles (offsets 2..32 keep parity groups separate) vs 60 before.

__device__ __forceinline__ void pair_layer(
    float r[4], float im[4],
    float cu, float su, float cv, float sv,
    float cS, float sS, float cD, float sD)
{
    // RX on u (high bit): butterflies (0,2),(1,3); new = c*a - i*s*a'
    {
        float t0r=r[0], t0i=im[0], t1r=r[2], t1i=im[2];
        r[0]=fmaf(cu,t0r, su*t1i); im[0]=fmaf(cu,t0i,-su*t1r);
        r[2]=fmaf(cu,t1r, su*t0i); im[2]=fmaf(cu,t1i,-su*t0r);
    }
    {
        float t0r=r[1], t0i=im[1], t1r=r[3], t1i=im[3];
        r[1]=fmaf(cu,t0r, su*t1i); im[1]=fmaf(cu,t0i,-su*t1r);
        r[3]=fmaf(cu,t1r, su*t0i); im[3]=fmaf(cu,t1i,-su*t0r);
    }
    // RX on v (low bit): butterflies (0,1),(2,3)
    {
        float t0r=r[0], t0i=im[0], t1r=r[1], t1i=im[1];
        r[0]=fmaf(cv,t0r, sv*t1i); im[0]=fmaf(cv,t0i,-sv*t1r);
        r[1]=fmaf(cv,t1r, sv*t0i); im[1]=fmaf(cv,t1i,-sv*t0r);
    }
    {
        float t0r=r[2], t0i=im[2], t1r=r[3], t1i=im[3];
        r[2]=fmaf(cv,t0r, sv*t1i); im[2]=fmaf(cv,t0i,-sv*t1r);
        r[3]=fmaf(cv,t1r, sv*t0i); im[3]=fmaf(cv,t1i,-sv*t0r);
    }
    // CNOT(u,v): swap indices 2,3 (register rename, free)
    { float tr=r[2]; r[2]=r[3]; r[3]=tr; float ti=im[2]; im[2]=im[3]; im[3]=ti; }
    // RZ diagonal
    {
        float rr, ii;
        rr=r[0]; ii=im[0];  r[0]=fmaf(rr,cS,  ii*sS); im[0]=fmaf(ii,cS, -rr*sS);
        rr=r[1]; ii=im[1];  r[1]=fmaf(rr,cD,  ii*sD); im[1]=fmaf(ii,cD, -rr*sD);
        rr=r[2]; ii=im[2];  r[2]=fmaf(rr,cD, -ii*sD); im[2]=fmaf(ii,cD,  rr*sD);
        rr=r[3]; ii=im[3];  r[3]=fmaf(rr,cS, -ii*sS); im[3]=fmaf(ii,cS,  rr*sS);
    }
}

__global__ __launch_bounds__(256) void quanv_fused(
    const float* __restrict__ x,     // [B,1,28,28]
    const float* __restrict__ qp,    // [LAYERS,WIRES]
    const float* __restrict__ Wt,    // [10,784]
    const float* __restrict__ bias,  // [10]
    float* __restrict__ out)         // [B,10]
{
    __shared__ float2 ph[LAYERS * 4];   // [(l*2+p)*2+d] = (cos, sin); d: 0=S 1=D
    __shared__ float wsum[4][10];

    const int b = blockIdx.x;
    const int t = threadIdx.x;

    // ---- RZ phase table: 12 sincos on idle wave-3 threads ----
    if (t >= 208 && t < 208 + LAYERS * 4) {
        const int j = t - 208;                     // j = l*4 + p*2 + d
        const int l = j >> 2, p = (j >> 1) & 1, d = j & 1;
        const float pu = qp[l*4 + 2*p], pv = qp[l*4 + 2*p + 1];
        float s, c;
        __sincosf(0.5f * (d ? (pu - pv) : (pu + pv)), &s, &c);
        ph[j] = make_float2(c, s);
    }

    // ---- patch pixel loads + RX sincos (overlaps table build) ----
    float cw[4], sw[4];
    if (t < PATCHES) {
        const int r = t / 14, cc = t % 14;
        const float* xb = x + (size_t)b * 784;
        const float2 top = *reinterpret_cast<const float2*>(xb + (2*r)*28 + 2*cc);
        const float2 bot = *reinterpret_cast<const float2*>(xb + (2*r+1)*28 + 2*cc);
        __sincosf(0.5f * top.x, &sw[0], &cw[0]);   // tl -> wire 0
        __sincosf(0.5f * top.y, &sw[1], &cw[1]);   // tr -> wire 1
        __sincosf(0.5f * bot.x, &sw[2], &cw[2]);   // bl -> wire 2
        __sincosf(0.5f * bot.y, &sw[3], &cw[3]);   // br -> wire 3
    }
    __syncthreads();

    float z[4] = {0.f, 0.f, 0.f, 0.f};
    if (t < PATCHES) {
        // ---- layer 1 analytic: amp_i = m_i * (-i)^popcount(i); CNOT perm
        //      (2<->3) and RZ[0] diagonal folded in ----
        float Ar[4], Ai[4], Br[4], Bi[4];
        {
            const float m0=cw[0]*cw[1], m1=cw[0]*sw[1], m2=sw[0]*cw[1], m3=sw[0]*sw[1];
            const float cs=ph[0].x, ss=ph[0].y, cd=ph[1].x, sd=ph[1].y;
            Ar[0]= m0*cs;  Ai[0]=-m0*ss;   // i=0 -> ti=0, pc=0
            Ar[1]=-m1*sd;  Ai[1]=-m1*cd;   // i=1 -> ti=1, pc=1
            Ar[3]= m2*ss;  Ai[3]=-m2*cs;   // i=2 -> ti=3, pc=1
            Ar[2]=-m3*cd;  Ai[2]=-m3*sd;   // i=3 -> ti=2, pc=2
        }
        {
            const float m0=cw[2]*cw[3], m1=cw[2]*sw[3], m2=sw[2]*cw[3], m3=sw[2]*sw[3];
            const float cs=ph[2].x, ss=ph[2].y, cd=ph[3].x, sd=ph[3].y;
            Br[0]= m0*cs;  Bi[0]=-m0*ss;
            Br[1]=-m1*sd;  Bi[1]=-m1*cd;
            Br[3]= m2*ss;  Bi[3]=-m2*cs;
            Br[2]=-m3*cd;  Bi[2]=-m3*sd;
        }

        // ---- layers 2..3: two independent 2-qubit circuits ----
        #pragma unroll
        for (int l = 1; l < LAYERS; ++l) {
            pair_layer(Ar, Ai, cw[0],sw[0], cw[1],sw[1],
                       ph[l*4+0].x, ph[l*4+0].y, ph[l*4+1].x, ph[l*4+1].y);
            pair_layer(Br, Bi, cw[2],sw[2], cw[3],sw[3],
                       ph[l*4+2].x, ph[l*4+2].y, ph[l*4+3].x, ph[l*4+3].y);
        }

        // ---- <Z_w> ----
        {
            const float p0=fmaf(Ar[0],Ar[0],Ai[0]*Ai[0]);
            const float p1=fmaf(Ar[1],Ar[1],Ai[1]*Ai[1]);
            const float p2=fmaf(Ar[2],Ar[2],Ai[2]*Ai[2]);
            const float p3=fmaf(Ar[3],Ar[3],Ai[3]*Ai[3]);
            z[0] = (p0+p1) - (p2+p3);   // wire 0 = high bit of pair A
            z[1] = (p0+p2) - (p1+p3);   // wire 1 = low bit
        }
        {
            const float p0=fmaf(Br[0],Br[0],Bi[0]*Bi[0]);
            const float p1=fmaf(Br[1],Br[1],Bi[1]*Bi[1]);
            const float p2=fmaf(Br[2],Br[2],Bi[2]*Bi[2]);
            const float p3=fmaf(Br[3],Br[3],Bi[3]*Bi[3]);
            z[2] = (p0+p1) - (p2+p3);   // wire 2
            z[3] = (p0+p2) - (p1+p3);   // wire 3
        }
    }

    // ---- linear layer: lane-parity class split over patch pairs ----
    // Exchange z with xor-1 neighbor; even lane computes classes 0-4 for
    // patches (t, t+1), odd lane classes 5-9 for the same pair.
    float oz[4];
    #pragma unroll
    for (int j = 0; j < 4; ++j) oz[j] = __shfl_xor(z[j], 1, 64);

    float part[5];
    if (t < PATCHES) {
        const int p0 = t & ~1;                  // even patch of the pair
        const int kbase = (t & 1) * 5;
        const float* zp0 = (t & 1) ? oz : z;    // z of patch p0
        const float* zp1 = (t & 1) ? z : oz;    // z of patch p0+1
        const float4* W4 = reinterpret_cast<const float4*>(Wt);  // [10][196]
        #pragma unroll
        for (int k = 0; k < 5; ++k) {
            const float4 w0 = W4[(kbase + k) * 196 + p0];
            const float4 w1 = W4[(kbase + k) * 196 + p0 + 1];
            float acc;
            acc = fmaf(zp0[0], w0.x, fmaf(zp0[1], w0.y, fmaf(zp0[2], w0.z, zp0[3] * w0.w)));
            acc = fmaf(zp1[0], w1.x, fmaf(zp1[1], w1.y, fmaf(zp1[2], w1.z, fmaf(zp1[3], w1.w, acc))));
            part[k] = acc;
        }
    } else {
        #pragma unroll
        for (int k = 0; k < 5; ++k) part[k] = 0.f;
    }
    // butterfly over offsets 2..32 keeps even/odd (class-group) lanes separate
    #pragma unroll
    for (int k = 0; k < 5; ++k) {
        #pragma unroll
        for (int off = 2; off <= 32; off <<= 1)
            part[k] += __shfl_xor(part[k], off, 64);
    }
    const int wave = t >> 6, lane = t & 63;
    if (lane < 2) {
        #pragma unroll
        for (int k = 0; k < 5; ++k) wsum[wave][lane * 5 + k] = part[k];
    }
    __syncthreads();

    // ---- cross-wave sum + log-softmax on 16 lanes (no second barrier) ----
    if (t < 16) {
        const float v = (t < 10)
            ? (bias[t] + wsum[0][t] + wsum[1][t] + wsum[2][t] + wsum[3][t])
            : -1e30f;
        float mx = v;
        #pragma unroll
        for (int off = 8; off > 0; off >>= 1)
            mx = fmaxf(mx, __shfl_xor(mx, off, 16));
        float se = (t < 10) ? expf(v - mx) : 0.f;
        #pragma unroll
        for (int off = 8; off > 0; off >>= 1)
            se += __shfl_xor(se, off, 16);
        if (t < 10)
            out[b * 10 + t] = v - (mx + logf(se));
    }
}

extern "C" void kernel_launch(void* const* d_in, const int* in_sizes, int n_in,
                              void* d_out, int out_size, void* d_ws, size_t ws_size,
                              hipStream_t stream) {
    const float* x    = (const float*)d_in[0];
    const float* qp   = (const float*)d_in[1];
    const float* W    = (const float*)d_in[2];
    const float* bias = (const float*)d_in[3];
    float* out = (float*)d_out;

    const int B = in_sizes[0] / 784;  // 1024
    quanv_fused<<<B, 256, 0, stream>>>(x, qp, W, bias, out);
}